// Round 21
// baseline (488.316 us; speedup 1.0000x reference)
//
#include <hip/hip_runtime.h>
#include <hip/hip_bf16.h>
#include <cstdint>
#include <cstddef>

// Problem constants
#define NTOK 49
#define DIM 384
#define KDIM 384
#define HEADS 12
#define HD 32
#define BATCH 2048
#define MROWS (BATCH * NTOK)   // 100352 = 392 * 256

typedef unsigned short u16;
typedef __bf16 bf16x8 __attribute__((ext_vector_type(8)));
typedef unsigned short u16x8 __attribute__((ext_vector_type(8)));
typedef float f32x4 __attribute__((ext_vector_type(4)));
typedef float f32x16 __attribute__((ext_vector_type(16)));

__device__ __forceinline__ u16 f2b(float f) {
  union { float f; unsigned u; } v; v.f = f;
  unsigned r = v.u + 0x7fffu + ((v.u >> 16) & 1u);   // RNE bf16
  return (u16)(r >> 16);
}

__device__ __forceinline__ bf16x8 ld_bf8(const u16* p) {
  u16x8 u = *(const u16x8*)p;
  return __builtin_bit_cast(bf16x8, u);
}

__device__ __forceinline__ void gload_lds16(const void* g, void* l) {
  __builtin_amdgcn_global_load_lds(
      (const __attribute__((address_space(1))) unsigned*)g,
      (__attribute__((address_space(3))) unsigned*)l, 16, 0, 0);
}

__device__ __forceinline__ unsigned pkbf(float lo, float hi) {
  unsigned r;
  asm("v_cvt_pk_bf16_f32 %0, %1, %2" : "=v"(r) : "v"(lo), "v"(hi));
  return r;
}

// ---------------- prep: weight casts + fused bias+mask table ----------------
// (x cast is now fused into the QKV GEMM staging)
// blocks [0,432): cast qkv_w; [432,576): proj_w; [576,3648): rpbm groups of 4.
__global__ __launch_bounds__(256) void k_prep(const float* __restrict__ qkv_w,
                                              u16* __restrict__ wqkvb,
                                              const float* __restrict__ proj_w,
                                              u16* __restrict__ wprojb,
                                              const float* __restrict__ bias_table,
                                              const float* __restrict__ mask,
                                              const int* __restrict__ rel_idx,
                                              float* __restrict__ rpbm) {
  int blk = blockIdx.x;
  if (blk < 576) {
    const float* in;
    u16* out;
    int i;
    if (blk < 432) { in = qkv_w; out = wqkvb; i = blk * 256 + threadIdx.x; }
    else           { in = proj_w; out = wprojb; i = (blk - 432) * 256 + threadIdx.x; }
    float4 v = ((const float4*)in)[i];
    ushort4 o;
    o.x = f2b(v.x); o.y = f2b(v.y); o.z = f2b(v.z); o.w = f2b(v.w);
    ((ushort4*)out)[i] = o;
  } else {
    int gidx = (blk - 576) * 256 + threadIdx.x;   // 786,432 groups of 4
    int l    = gidx & 63;
    int rq   = (gidx >> 6) & 3;
    int tile = (gidx >> 8) & 3;
    int w    = (gidx >> 10) & 63;
    int h    = gidx >> 16;
    int mi = tile >> 1, nj = tile & 1;
    int kk0 = mi * 32 + 8 * rq + 4 * (l >> 5);
    int qq  = nj * 32 + (l & 31);
    float4 out;
    float* op = (float*)&out;
#pragma unroll
    for (int rl = 0; rl < 4; ++rl) {
      int kk = kk0 + rl;
      float v = -1e30f;
      if (kk < NTOK && qq < NTOK)
        v = bias_table[rel_idx[qq * NTOK + kk] * HEADS + h] +
            mask[(w * NTOK + qq) * NTOK + kk];
      op[rl] = v;
    }
    ((float4*)rpbm)[gidx] = out;
  }
}

// ------- QKV GEMM, cast-fused A (f32 x), T14 split staging ------------------
// Same 256x128 / 3-buf / one-barrier schedule as the verified k_gemm256, but
// A is staged from f32: iter t ISSUES 4 dwordx4 (tile t+3 -> regs); iter t+1
// CONVERTS (8 cvt_pk) + 2 ds_write_b128 (tile t+3 -> buf). LDS image is
// byte-identical to the gload path (X(row) = (row>>1)&3 swizzle), so
// FRAGREAD/MFMA/epilogue are unchanged. vmcnt: 5 VMEM/iter (4 A-f32 + 1 B);
// steady vmcnt(5) guarantees B(t+1); A f32 deps are compiler-tracked.
__global__ __launch_bounds__(512, 4) void k_gemmqkv(const float* __restrict__ Xf,
                                                    const u16* __restrict__ B,
                                                    const float* __restrict__ bias,
                                                    u16* __restrict__ C) {
  __shared__ u16 sh[36864];   // 72 KB: 3 x (A 16KB + B 8KB); epilogue reuses 64KB
  int bid = blockIdx.x;
  int tile = (bid & 7) * 441 + (bid >> 3);   // XCD-contiguous (3528 = 8*441)
  int mt = tile / 9, nt = tile - mt * 9;
  long m0 = (long)mt * 256;
  int n0 = nt * 128;
  int tid = threadIdx.x;
  int lane = tid & 63, wid = tid >> 6;           // 8 waves
  int wr = (wid >> 1) * 64, wc = (wid & 1) * 64; // 4M x 2N wave grid
  int c = lane & 15, g = lane >> 4;
  int gsw = (g ^ ((c >> 1) & 3)) * 8;            // swizzled read segment

  // B staging (unchanged gload path)
  int srow = wid * 16 + (lane >> 2);             // 0..127
  int scol = ((lane & 3) ^ ((lane >> 3) & 3)) * 8;
  const u16* gB = B + (long)(n0 + srow) * KDIM + scol;
  int lrow = srow, lseg = (lane & 3) * 8;

  // A staging: thread covers (row ar, half ahf) = 16 f32 per K-step
  int ar = tid >> 1;                 // 0..255
  int ahf = tid & 1;                 // 0..1 (logical col segs {2hf, 2hf+1})
  const float* gAf = Xf + (m0 + ar) * 384 + ahf * 16;
  int aX = (ar >> 1) & 3;            // row swizzle
  int ap0 = (2 * ahf) ^ aX;          // physical seg for logical 2hf
  int ap1 = (2 * ahf + 1) ^ aX;      // physical seg for logical 2hf+1
  int abase = ar * 64;               // byte offset of row within A-part

  f32x4 acc[4][4] = {};
  bf16x8 af[4], bfr[4];
  float4 a0, a1, a2, a3;             // held f32 staging regs (one tile)

#define ALOAD(KT)                                                              \
  {                                                                            \
    a0 = *(const float4*)(gAf + (KT));                                         \
    a1 = *(const float4*)(gAf + (KT) + 4);                                     \
    a2 = *(const float4*)(gAf + (KT) + 8);                                     \
    a3 = *(const float4*)(gAf + (KT) + 12);                                    \
  }

#define AWRITE(BUF)                                                            \
  {                                                                            \
    char* Ab = (char*)sh + (BUF) * 24576;                                      \
    uint4 w0, w1;                                                              \
    w0.x = pkbf(a0.x, a0.y); w0.y = pkbf(a0.z, a0.w);                          \
    w0.z = pkbf(a1.x, a1.y); w0.w = pkbf(a1.z, a1.w);                          \
    w1.x = pkbf(a2.x, a2.y); w1.y = pkbf(a2.z, a2.w);                          \
    w1.z = pkbf(a3.x, a3.y); w1.w = pkbf(a3.z, a3.w);                          \
    *(uint4*)(Ab + abase + ap0 * 16) = w0;                                     \
    *(uint4*)(Ab + abase + ap1 * 16) = w1;                                     \
  }

#define BSTAGE(BUF, KT)                                                        \
  gload_lds16(gB + (KT), &sh[(BUF) * 12288 + 8192 + lrow * 32 + lseg]);

#define FRAGREAD(BUF)                                                          \
  {                                                                            \
    const u16* As = sh + (BUF) * 12288;                                        \
    const u16* Bs = As + 8192;                                                 \
    _Pragma("unroll") for (int i = 0; i < 4; ++i) {                            \
      af[i]  = ld_bf8(&As[(wr + i * 16 + c) * 32 + gsw]);                      \
      bfr[i] = ld_bf8(&Bs[(wc + i * 16 + c) * 32 + gsw]);                      \
    }                                                                          \
  }

#define MFMA_CL                                                                \
  __builtin_amdgcn_s_setprio(1);                                               \
  _Pragma("unroll") for (int mi = 0; mi < 4; ++mi)                             \
  _Pragma("unroll") for (int ni = 0; ni < 4; ++ni)                             \
      acc[mi][ni] = __builtin_amdgcn_mfma_f32_16x16x32_bf16(                   \
          af[mi], bfr[ni], acc[mi][ni], 0, 0, 0);                              \
  __builtin_amdgcn_s_setprio(0);

#define GITERQ(T, NV)                                                          \
  {                                                                            \
    MFMA_CL;                                                                   \
    asm volatile("s_waitcnt vmcnt(" #NV ") lgkmcnt(0)" ::: "memory");          \
    __builtin_amdgcn_s_barrier();                                              \
    __builtin_amdgcn_sched_barrier(0);                                         \
    if ((T) + 2 < 12) AWRITE(((T) + 2) % 3);       /* regs from iter T-1 */    \
    if ((T) + 3 < 12) { ALOAD(((T) + 3) * 32); BSTAGE((T) % 3, ((T) + 3) * 32); } \
    FRAGREAD(((T) + 1) % 3);                                                   \
  }

  // prologue: tiles 0,1 direct (load->cvt->write), B 0..2, tile-2 regs held
  ALOAD(0);  AWRITE(0);
  ALOAD(32); AWRITE(1);
  BSTAGE(0, 0);
  BSTAGE(1, 32);
  BSTAGE(2, 64);
  ALOAD(64);                         // tile 2, written at iter 0
  asm volatile("s_waitcnt vmcnt(6) lgkmcnt(0)" ::: "memory");  // B(0) done
  __builtin_amdgcn_s_barrier();
  __builtin_amdgcn_sched_barrier(0);
  FRAGREAD(0);

  GITERQ(0, 5)  GITERQ(1, 5)  GITERQ(2, 5)  GITERQ(3, 5)
  GITERQ(4, 5)  GITERQ(5, 5)  GITERQ(6, 5)  GITERQ(7, 5)
  GITERQ(8, 5)  GITERQ(9, 5)  GITERQ(10, 0)
  { MFMA_CL; }   // iter 11: pure MFMA
  __builtin_amdgcn_s_barrier();
#undef GITERQ
#undef MFMA_CL
#undef FRAGREAD
#undef BSTAGE
#undef AWRITE
#undef ALOAD

  // ---- epilogue: head-major qkv [t][h][b][tok][d] = [3][12][2048][49][32] --
#pragma unroll
  for (int mi = 0; mi < 4; ++mi)
#pragma unroll
    for (int ni = 0; ni < 4; ++ni) {
      int col = wc + ni * 16 + c;
      float bv = bias[n0 + col];
#pragma unroll
      for (int r = 0; r < 4; ++r) {
        int row = wr + mi * 16 + g * 4 + r;       // 0..255
        sh[row * 128 + col] = f2b(acc[mi][ni][r] + bv);
      }
    }
  __syncthreads();
#pragma unroll
  for (int rep = 0; rep < 8; ++rep) {
    int idx = rep * 4096 + tid * 8;      // u16 units; 32768 total
    int row = idx >> 7, col = idx & 127;
    int grow = (int)m0 + row;
    int b = grow / 49, tok = grow - b * 49;
    int gcol = n0 + col;
    int t = gcol / 384;
    int hc = gcol - t * 384;
    int h = hc >> 5, d0 = hc & 31;
    size_t off = (((size_t)(t * 12 + h) * BATCH + b) * 49 + tok) * 32 + d0;
    *(u16x8*)(C + off) = *(const u16x8*)&sh[idx];
  }
}

// ------- proj GEMM: round-14 verified 256x128, 3-buf counted vmcnt ----------
template <int NTN, int GD8>
__global__ __launch_bounds__(512, 4) void k_gemm256(const u16* __restrict__ A,
                                                    const u16* __restrict__ B,
                                                    const float* __restrict__ bias,
                                                    float* __restrict__ C) {
  __shared__ u16 sh[36864];
  int bid = blockIdx.x;
  int tile = (bid & 7) * GD8 + (bid >> 3);
  int mt = tile / NTN, nt = tile - mt * NTN;
  long m0 = (long)mt * 256;
  int n0 = nt * 128;
  int tid = threadIdx.x;
  int lane = tid & 63, wid = tid >> 6;
  int wr = (wid >> 1) * 64, wc = (wid & 1) * 64;
  int c = lane & 15, g = lane >> 4;
  int gsw = (g ^ ((c >> 1) & 3)) * 8;

  int srow = wid * 16 + (lane >> 2);
  int scol = ((lane & 3) ^ ((lane >> 3) & 3)) * 8;
  const u16* gA = A + (m0 + srow) * (long)KDIM + scol;
  const u16* gB = B + (long)(n0 + srow) * KDIM + scol;
  int lrow = srow, lseg = (lane & 3) * 8;

  f32x4 acc[4][4] = {};
  bf16x8 af[4], bfr[4];

#define STAGE256(BUF, KT)                                                      \
  {                                                                            \
    u16* As_ = sh + (BUF) * 12288;                                             \
    u16* Bs_ = As_ + 8192;                                                     \
    gload_lds16(gA + (KT), &As_[lrow * 32 + lseg]);                            \
    gload_lds16(gA + (KT) + 128L * KDIM, &As_[(lrow + 128) * 32 + lseg]);      \
    gload_lds16(gB + (KT), &Bs_[lrow * 32 + lseg]);                            \
  }

#define FRAGREAD(BUF)                                                          \
  {                                                                            \
    const u16* As = sh + (BUF) * 12288;                                        \
    const u16* Bs = As + 8192;                                                 \
    _Pragma("unroll") for (int i = 0; i < 4; ++i) {                            \
      af[i]  = ld_bf8(&As[(wr + i * 16 + c) * 32 + gsw]);                      \
      bfr[i] = ld_bf8(&Bs[(wc + i * 16 + c) * 32 + gsw]);                      \
    }                                                                          \
  }

#define MFMA_CL                                                                \
  __builtin_amdgcn_s_setprio(1);                                               \
  _Pragma("unroll") for (int mi = 0; mi < 4; ++mi)                             \
  _Pragma("unroll") for (int ni = 0; ni < 4; ++ni)                             \
      acc[mi][ni] = __builtin_amdgcn_mfma_f32_16x16x32_bf16(                   \
          af[mi], bfr[ni], acc[mi][ni], 0, 0, 0);                              \
  __builtin_amdgcn_s_setprio(0);

#define GITER(T, NV)                                                           \
  {                                                                            \
    MFMA_CL;                                                                   \
    asm volatile("s_waitcnt vmcnt(" #NV ")" ::: "memory");                     \
    __builtin_amdgcn_s_barrier();                                              \
    __builtin_amdgcn_sched_barrier(0);                                         \
    if ((T) + 3 < 12) STAGE256((T) % 3, ((T) + 3) * 32);                       \
    FRAGREAD(((T) + 1) % 3);                                                   \
  }

  STAGE256(0, 0);
  STAGE256(1, 32);
  STAGE256(2, 64);
  asm volatile("s_waitcnt vmcnt(6)" ::: "memory");
  __builtin_amdgcn_s_barrier();
  __builtin_amdgcn_sched_barrier(0);
  FRAGREAD(0);

  GITER(0, 3)  GITER(1, 3)  GITER(2, 3)  GITER(3, 3)
  GITER(4, 3)  GITER(5, 3)  GITER(6, 3)  GITER(7, 3)
  GITER(8, 3)  GITER(9, 3)  GITER(10, 0)
  { MFMA_CL; }
  __builtin_amdgcn_s_barrier();
#undef GITER
#undef MFMA_CL
#undef FRAGREAD
#undef STAGE256

  float* shf = (float*)sh;
#pragma unroll
  for (int chunk = 0; chunk < 2; ++chunk) {
    __syncthreads();
    if ((wid >> 2) == chunk) {
#pragma unroll
      for (int mi = 0; mi < 4; ++mi)
#pragma unroll
        for (int ni = 0; ni < 4; ++ni) {
          int col = wc + ni * 16 + c;
          float bv = bias[n0 + col];
#pragma unroll
          for (int r = 0; r < 4; ++r) {
            int lr = ((wid >> 1) & 1) * 64 + mi * 16 + g * 4 + r;
            shf[lr * 128 + col] = acc[mi][ni][r] + bv;
          }
        }
    }
    __syncthreads();
#pragma unroll
    for (int rep = 0; rep < 8; ++rep) {
      int idx = rep * 2048 + tid * 4;
      int row = idx >> 7, col = idx & 127;
      *(float4*)(C + (m0 + chunk * 128 + row) * 384 + n0 + col) =
          *(const float4*)&shf[idx];
    }
  }
}

// -------- fused window attention: round-19 verified (no LDS, mirrored PV) ---
__global__ __launch_bounds__(256, 4) void k_attn(const u16* __restrict__ qkv,
                                                 const float* __restrict__ rpbmT,
                                                 u16* __restrict__ attnout) {
  int lane = threadIdx.x & 63, wid = threadIdx.x >> 6;
  int blk0 = blockIdx.x;                 // grid 6144 = 8 * 768
  int blk = (blk0 & 7) * 768 + (blk0 >> 3);   // XCD-contiguous mapping
  int w = blk / 96;
  int rr = blk - w * 96;
  int j = rr / 3;
  int hb = rr - j * 3;
  int b = j * 64 + w;
  int h = hb * 4 + wid;
  int l31 = lane & 31, hi = lane >> 5;

  const u16* qh = qkv + ((size_t)(h)*BATCH + b) * (49 * 32);
  const u16* kh = qkv + ((size_t)(12 + h) * BATCH + b) * (49 * 32);
  const u16* vh = qkv + ((size_t)(24 + h) * BATCH + b) * (49 * 32);

  bf16x8 kf[2][2], qf[2][2];
#pragma unroll
  for (int mi = 0; mi < 2; ++mi) {
    int row = mi * 32 + l31; if (row > NTOK - 1) row = NTOK - 1;
#pragma unroll
    for (int k2 = 0; k2 < 2; ++k2)
      kf[mi][k2] = ld_bf8(kh + row * 32 + k2 * 16 + hi * 8);
  }
#pragma unroll
  for (int nj = 0; nj < 2; ++nj) {
    int row = nj * 32 + l31; if (row > NTOK - 1) row = NTOK - 1;
#pragma unroll
    for (int k2 = 0; k2 < 2; ++k2)
      qf[nj][k2] = ld_bf8(qh + row * 32 + k2 * 16 + hi * 8);
  }

  f32x16 s[2][2];
  f32x16 z16 = {};
#pragma unroll
  for (int mi = 0; mi < 2; ++mi)
#pragma unroll
    for (int nj = 0; nj < 2; ++nj) {
      s[mi][nj] = __builtin_amdgcn_mfma_f32_32x32x16_bf16(kf[mi][0], qf[nj][0],
                                                          z16, 0, 0, 0);
      s[mi][nj] = __builtin_amdgcn_mfma_f32_32x32x16_bf16(kf[mi][1], qf[nj][1],
                                                          s[mi][nj], 0, 0, 0);
    }

  const float scale = 0.17677669529663687f;   // 32^-0.5
  const f32x4* rp = (const f32x4*)(rpbmT + ((size_t)(h * 64 + w)) * 4096);
#pragma unroll
  for (int mi = 0; mi < 2; ++mi)
#pragma unroll
    for (int nj = 0; nj < 2; ++nj)
#pragma unroll
      for (int rq = 0; rq < 4; ++rq) {
        f32x4 rv = rp[(mi * 2 + nj) * 256 + rq * 64 + lane];
#pragma unroll
        for (int rl = 0; rl < 4; ++rl)
          s[mi][nj][rq * 4 + rl] = s[mi][nj][rq * 4 + rl] * scale + rv[rl];
      }

#pragma unroll
  for (int nj = 0; nj < 2; ++nj) {
    float mx = s[0][nj][0];
#pragma unroll
    for (int mi = 0; mi < 2; ++mi)
#pragma unroll
      for (int r = 0; r < 16; ++r)
        mx = fmaxf(mx, s[mi][nj][r]);
    mx = fmaxf(mx, __shfl_xor(mx, 32));
    float sum = 0.f;
#pragma unroll
    for (int mi = 0; mi < 2; ++mi)
#pragma unroll
      for (int r = 0; r < 16; ++r) {
        float p = __expf(s[mi][nj][r] - mx);
        s[mi][nj][r] = p;
        sum += p;
      }
    sum += __shfl_xor(sum, 32);
    float inv = __builtin_amdgcn_rcpf(sum);
#pragma unroll
    for (int mi = 0; mi < 2; ++mi)
#pragma unroll
      for (int r = 0; r < 16; ++r)
        s[mi][nj][r] *= inv;
  }

  f32x16 o[2] = {};
#pragma unroll
  for (int kk = 0; kk < 4; ++kk) {
    u16x8 tmp;
#pragma unroll
    for (int e = 0; e < 8; ++e)
      tmp[e] = vh[(kk * 16 + hi * 8 + e) * 32 + l31];
    bf16x8 vbk = __builtin_bit_cast(bf16x8, tmp);
#pragma unroll
    for (int nj = 0; nj < 2; ++nj) {
      const int mi = kk >> 1, br = (kk & 1) * 8;
      unsigned t0 = pkbf(s[mi][nj][br + 0], s[mi][nj][br + 1]);
      unsigned t1 = pkbf(s[mi][nj][br + 2], s[mi][nj][br + 3]);
      unsigned t2 = pkbf(s[mi][nj][br + 4], s[mi][nj][br + 5]);
      unsigned t3 = pkbf(s[mi][nj][br + 6], s[mi][nj][br + 7]);
      asm("v_permlane32_swap_b32 %0, %1" : "+v"(t0), "+v"(t2));
      asm("v_permlane32_swap_b32 %0, %1" : "+v"(t1), "+v"(t3));
      uint4 uu; uu.x = t0; uu.y = t1; uu.z = t2; uu.w = t3;
      bf16x8 pa = __builtin_bit_cast(bf16x8, uu);
      o[nj] = __builtin_amdgcn_mfma_f32_32x32x16_bf16(pa, vbk, o[nj], 0, 0, 0);
    }
  }

  u16* obase = attnout + (size_t)b * (NTOK * DIM) + h * HD;
#pragma unroll
  for (int nj = 0; nj < 2; ++nj)
#pragma unroll
    for (int r = 0; r < 16; ++r) {
      int q = nj * 32 + (r & 3) + 8 * (r >> 2) + 4 * hi;
      if (q < NTOK)
        obase[(size_t)q * DIM + l31] = f2b(o[nj][r]);
    }
}

// ---------------------------------------------------------------------------
extern "C" void kernel_launch(void* const* d_in, const int* in_sizes, int n_in,
                              void* d_out, int out_size, void* d_ws, size_t ws_size,
                              hipStream_t stream) {
  const float* x       = (const float*)d_in[0];
  const float* qkv_w   = (const float*)d_in[1];
  const float* qkv_b   = (const float*)d_in[2];
  const float* proj_w  = (const float*)d_in[3];
  const float* proj_b  = (const float*)d_in[4];
  const float* bias_tb = (const float*)d_in[5];
  const float* mask    = (const float*)d_in[6];
  const int*   rel_idx = (const int*)d_in[7];
  float* out = (float*)d_out;

  char* ws = (char*)d_ws;
  u16*   attnout = (u16*)(ws + 0);                  //  77,070,336  attn out bf16
  u16*   wqkvb   = (u16*)(ws + 77070336);           //     884,736  qkv_w bf16
  u16*   wprojb  = (u16*)(ws + 77955072);           //     294,912  proj_w bf16
  float* rpbm    = (float*)(ws + 78249984);         //  12,582,912  bias+mask
  u16*   qkv     = (u16*)(ws + 90832896);           // 231,211,008  qkv head-major

  // 1) prep: weight casts + 32x32-layout bias+mask table (x cast fused away)
  k_prep<<<3648, 256, 0, stream>>>(qkv_w, wqkvb, proj_w, wprojb,
                                   bias_tb, mask, rel_idx, rpbm);

  // 2) QKV GEMM, cast-fused f32 A -> head-major qkv [3][12][2048][49][32]
  k_gemmqkv<<<3528, 512, 0, stream>>>(x, wqkvb, qkv_b, qkv);

  // 3) window attention (round-19 verified) -> bf16 [100352,384]
  k_attn<<<6144, 256, 0, stream>>>(qkv, rpbm, attnout);

  // 4) proj GEMM: [100352,384] x [384,384]^T + bias -> f32 d_out
  k_gemm256<3, 147><<<1176, 512, 0, stream>>>(attnout, wprojb, proj_b, out);

  (void)in_sizes; (void)n_in; (void)out_size; (void)ws_size;
}

// Round 22
// 335.509 us; speedup vs baseline: 1.4554x; 1.4554x over previous
//
#include <hip/hip_runtime.h>
#include <hip/hip_bf16.h>
#include <cstdint>
#include <cstddef>

// Problem constants
#define NTOK 49
#define DIM 384
#define KDIM 384
#define HEADS 12
#define HD 32
#define BATCH 2048
#define MROWS (BATCH * NTOK)   // 100352 = 392 * 256

typedef unsigned short u16;
typedef __bf16 bf16x8 __attribute__((ext_vector_type(8)));
typedef unsigned short u16x8 __attribute__((ext_vector_type(8)));
typedef float f32x4 __attribute__((ext_vector_type(4)));
typedef float f32x16 __attribute__((ext_vector_type(16)));

__device__ __forceinline__ u16 f2b(float f) {
  union { float f; unsigned u; } v; v.f = f;
  unsigned r = v.u + 0x7fffu + ((v.u >> 16) & 1u);   // RNE bf16
  return (u16)(r >> 16);
}

__device__ __forceinline__ bf16x8 ld_bf8(const u16* p) {
  u16x8 u = *(const u16x8*)p;
  return __builtin_bit_cast(bf16x8, u);
}

__device__ __forceinline__ void gload_lds16(const void* g, void* l) {
  __builtin_amdgcn_global_load_lds(
      (const __attribute__((address_space(1))) unsigned*)g,
      (__attribute__((address_space(3))) unsigned*)l, 16, 0, 0);
}

__device__ __forceinline__ unsigned pkbf(float lo, float hi) {
  unsigned r;
  asm("v_cvt_pk_bf16_f32 %0, %1, %2" : "=v"(r) : "v"(lo), "v"(hi));
  return r;
}

// ---------------- prep: x/w casts + fused bias+mask table -------------------
// rpbm layout matches the 32x32 MFMA C-layout of S^T = K·Q^T (round-14..19).
__global__ __launch_bounds__(256) void k_prep(const float* __restrict__ x,
                                              u16* __restrict__ xb,
                                              const float* __restrict__ qkv_w,
                                              u16* __restrict__ wqkvb,
                                              const float* __restrict__ proj_w,
                                              u16* __restrict__ wprojb,
                                              const float* __restrict__ bias_table,
                                              const float* __restrict__ mask,
                                              const int* __restrict__ rel_idx,
                                              float* __restrict__ rpbm) {
  int blk = blockIdx.x;
  if (blk < 38208) {
    const float* in;
    u16* out;
    int i;
    if (blk < 37632) {
      in = x; out = xb; i = blk * 256 + threadIdx.x;
    } else if (blk < 38064) {
      in = qkv_w; out = wqkvb; i = (blk - 37632) * 256 + threadIdx.x;
    } else {
      in = proj_w; out = wprojb; i = (blk - 38064) * 256 + threadIdx.x;
    }
    float4 v = ((const float4*)in)[i];
    ushort4 o;
    o.x = f2b(v.x); o.y = f2b(v.y); o.z = f2b(v.z); o.w = f2b(v.w);
    ((ushort4*)out)[i] = o;
  } else {
    int gidx = (blk - 38208) * 256 + threadIdx.x;   // 786,432 groups of 4
    int l    = gidx & 63;
    int rq   = (gidx >> 6) & 3;
    int tile = (gidx >> 8) & 3;
    int w    = (gidx >> 10) & 63;
    int h    = gidx >> 16;
    int mi = tile >> 1, nj = tile & 1;
    int kk0 = mi * 32 + 8 * rq + 4 * (l >> 5);
    int qq  = nj * 32 + (l & 31);
    float4 out;
    float* op = (float*)&out;
#pragma unroll
    for (int rl = 0; rl < 4; ++rl) {
      int kk = kk0 + rl;
      float v = -1e30f;
      if (kk < NTOK && qq < NTOK)
        v = bias_table[rel_idx[qq * NTOK + kk] * HEADS + h] +
            mask[(w * NTOK + qq) * NTOK + kk];
      op[rl] = v;
    }
    ((float4*)rpbm)[gidx] = out;
  }
}

// ------- NT GEMM: 256x128 tile, 512 thr / 8 waves, 3-buf counted vmcnt ------
// Round-14 verified structure. OUT_BF16=1 (QKV): head-major epilogue
// [3][12][BATCH][49][32]; OUT_BF16=0 (proj): f32 row-major.
template <int OUT_BF16, int NCOLS, int NTN, int GD8>
__global__ __launch_bounds__(512, 4) void k_gemm256(const u16* __restrict__ A,
                                                    const u16* __restrict__ B,
                                                    const float* __restrict__ bias,
                                                    void* __restrict__ Cv) {
  __shared__ u16 sh[36864];   // 72 KB: 3 x 24 KB; epilogue reuses 64 KB
  int bid = blockIdx.x;
  int tile = (bid & 7) * GD8 + (bid >> 3);   // XCD-contiguous (grid % 8 == 0)
  int mt = tile / NTN, nt = tile - mt * NTN;
  long m0 = (long)mt * 256;
  int n0 = nt * 128;
  int tid = threadIdx.x;
  int lane = tid & 63, wid = tid >> 6;           // 8 waves
  int wr = (wid >> 1) * 64, wc = (wid & 1) * 64; // 4M x 2N wave grid
  int c = lane & 15, g = lane >> 4;
  int gsw = (g ^ ((c >> 1) & 3)) * 8;            // swizzled read segment

  int srow = wid * 16 + (lane >> 2);             // 0..127
  int scol = ((lane & 3) ^ ((lane >> 3) & 3)) * 8;  // pre-swizzled global seg
  const u16* gA = A + (m0 + srow) * (long)KDIM + scol;
  const u16* gB = B + (long)(n0 + srow) * KDIM + scol;
  int lrow = srow, lseg = (lane & 3) * 8;        // linear LDS dest

  f32x4 acc[4][4] = {};
  bf16x8 af[4], bfr[4];

#define STAGE256(BUF, KT)                                                      \
  {                                                                            \
    u16* As_ = sh + (BUF) * 12288;                                             \
    u16* Bs_ = As_ + 8192;                                                     \
    gload_lds16(gA + (KT), &As_[lrow * 32 + lseg]);                            \
    gload_lds16(gA + (KT) + 128L * KDIM, &As_[(lrow + 128) * 32 + lseg]);      \
    gload_lds16(gB + (KT), &Bs_[lrow * 32 + lseg]);                            \
  }

#define FRAGREAD(BUF)                                                          \
  {                                                                            \
    const u16* As = sh + (BUF) * 12288;                                        \
    const u16* Bs = As + 8192;                                                 \
    _Pragma("unroll") for (int i = 0; i < 4; ++i) {                            \
      af[i]  = ld_bf8(&As[(wr + i * 16 + c) * 32 + gsw]);                      \
      bfr[i] = ld_bf8(&Bs[(wc + i * 16 + c) * 32 + gsw]);                      \
    }                                                                          \
  }

#define MFMA_CL                                                                \
  __builtin_amdgcn_s_setprio(1);                                               \
  _Pragma("unroll") for (int mi = 0; mi < 4; ++mi)                             \
  _Pragma("unroll") for (int ni = 0; ni < 4; ++ni)                             \
      acc[mi][ni] = __builtin_amdgcn_mfma_f32_16x16x32_bf16(                   \
          af[mi], bfr[ni], acc[mi][ni], 0, 0, 0);                              \
  __builtin_amdgcn_s_setprio(0);

#define GITER(T, NV)                                                           \
  {                                                                            \
    MFMA_CL;                                                                   \
    asm volatile("s_waitcnt vmcnt(" #NV ")" ::: "memory");                     \
    __builtin_amdgcn_s_barrier();                                              \
    __builtin_amdgcn_sched_barrier(0);                                         \
    if ((T) + 3 < 12) STAGE256((T) % 3, ((T) + 3) * 32);                       \
    FRAGREAD(((T) + 1) % 3);                                                   \
  }

  STAGE256(0, 0);
  STAGE256(1, 32);
  STAGE256(2, 64);
  asm volatile("s_waitcnt vmcnt(6)" ::: "memory");
  __builtin_amdgcn_s_barrier();
  __builtin_amdgcn_sched_barrier(0);
  FRAGREAD(0);

  GITER(0, 3)  GITER(1, 3)  GITER(2, 3)  GITER(3, 3)
  GITER(4, 3)  GITER(5, 3)  GITER(6, 3)  GITER(7, 3)
  GITER(8, 3)  GITER(9, 3)  GITER(10, 0)
  { MFMA_CL; }   // iter 11: pure MFMA
  __builtin_amdgcn_s_barrier();   // tile-11 reads retired before epilogue
#undef GITER
#undef MFMA_CL
#undef FRAGREAD
#undef STAGE256

  if (OUT_BF16) {
    // head-major qkv out: [t][h][b][tok][d] = [3][12][2048][49][32]
    u16* C = (u16*)Cv;
#pragma unroll
    for (int mi = 0; mi < 4; ++mi)
#pragma unroll
      for (int ni = 0; ni < 4; ++ni) {
        int col = wc + ni * 16 + c;
        float bv = bias[n0 + col];
#pragma unroll
        for (int r = 0; r < 4; ++r) {
          int row = wr + mi * 16 + g * 4 + r;       // 0..255
          sh[row * 128 + col] = f2b(acc[mi][ni][r] + bv);
        }
      }
    __syncthreads();
#pragma unroll
    for (int rep = 0; rep < 8; ++rep) {
      int idx = rep * 4096 + tid * 8;      // u16 units; 32768 total
      int row = idx >> 7, col = idx & 127;
      int grow = (int)m0 + row;
      int b = grow / 49, tok = grow - b * 49;     // const-div -> magic mul
      int gcol = n0 + col;
      int t = gcol / 384;
      int hc = gcol - t * 384;
      int h = hc >> 5, d0 = hc & 31;
      size_t off = (((size_t)(t * 12 + h) * BATCH + b) * 49 + tok) * 32 + d0;
      *(u16x8*)(C + off) = *(const u16x8*)&sh[idx];
    }
  } else {
    float* C = (float*)Cv;
    float* shf = (float*)sh;               // 128 rows x 128 cols f32 = 64 KB
#pragma unroll
    for (int chunk = 0; chunk < 2; ++chunk) {
      __syncthreads();
      if ((wid >> 2) == chunk) {
#pragma unroll
        for (int mi = 0; mi < 4; ++mi)
#pragma unroll
          for (int ni = 0; ni < 4; ++ni) {
            int col = wc + ni * 16 + c;
            float bv = bias[n0 + col];
#pragma unroll
            for (int r = 0; r < 4; ++r) {
              int lr = ((wid >> 1) & 1) * 64 + mi * 16 + g * 4 + r;
              shf[lr * 128 + col] = acc[mi][ni][r] + bv;
            }
          }
      }
      __syncthreads();
#pragma unroll
      for (int rep = 0; rep < 8; ++rep) {
        int idx = rep * 2048 + tid * 4;
        int row = idx >> 7, col = idx & 127;
        *(float4*)(C + (m0 + chunk * 128 + row) * NCOLS + n0 + col) =
            *(const float4*)&shf[idx];
      }
    }
  }
}

// -------- fused window attention: 32x32 MFMA, NO LDS, mirrored PV -----------
// Round-19 verified structure + setprio around both MFMA clusters (m191).
__global__ __launch_bounds__(256, 4) void k_attn(const u16* __restrict__ qkv,
                                                 const float* __restrict__ rpbmT,
                                                 u16* __restrict__ attnout) {
  int lane = threadIdx.x & 63, wid = threadIdx.x >> 6;
  int blk0 = blockIdx.x;                 // grid 6144 = 8 * 768
  int blk = (blk0 & 7) * 768 + (blk0 >> 3);   // XCD-contiguous mapping
  int w = blk / 96;
  int rr = blk - w * 96;
  int j = rr / 3;
  int hb = rr - j * 3;
  int b = j * 64 + w;
  int h = hb * 4 + wid;
  int l31 = lane & 31, hi = lane >> 5;

  const u16* qh = qkv + ((size_t)(h)*BATCH + b) * (49 * 32);
  const u16* kh = qkv + ((size_t)(12 + h) * BATCH + b) * (49 * 32);
  const u16* vh = qkv + ((size_t)(24 + h) * BATCH + b) * (49 * 32);

  bf16x8 kf[2][2], qf[2][2];
#pragma unroll
  for (int mi = 0; mi < 2; ++mi) {
    int row = mi * 32 + l31; if (row > NTOK - 1) row = NTOK - 1;
#pragma unroll
    for (int k2 = 0; k2 < 2; ++k2)
      kf[mi][k2] = ld_bf8(kh + row * 32 + k2 * 16 + hi * 8);
  }
#pragma unroll
  for (int nj = 0; nj < 2; ++nj) {
    int row = nj * 32 + l31; if (row > NTOK - 1) row = NTOK - 1;
#pragma unroll
    for (int k2 = 0; k2 < 2; ++k2)
      qf[nj][k2] = ld_bf8(qh + row * 32 + k2 * 16 + hi * 8);
  }

  // ---- S^T[k][q] = K Q^T ----
  f32x16 s[2][2];
  f32x16 z16 = {};
  __builtin_amdgcn_s_setprio(1);
#pragma unroll
  for (int mi = 0; mi < 2; ++mi)
#pragma unroll
    for (int nj = 0; nj < 2; ++nj) {
      s[mi][nj] = __builtin_amdgcn_mfma_f32_32x32x16_bf16(kf[mi][0], qf[nj][0],
                                                          z16, 0, 0, 0);
      s[mi][nj] = __builtin_amdgcn_mfma_f32_32x32x16_bf16(kf[mi][1], qf[nj][1],
                                                          s[mi][nj], 0, 0, 0);
    }
  __builtin_amdgcn_s_setprio(0);

  // ---- scale + pre-swizzled bias+mask (32x32 layout) ----
  const float scale = 0.17677669529663687f;   // 32^-0.5
  const f32x4* rp = (const f32x4*)(rpbmT + ((size_t)(h * 64 + w)) * 4096);
#pragma unroll
  for (int mi = 0; mi < 2; ++mi)
#pragma unroll
    for (int nj = 0; nj < 2; ++nj)
#pragma unroll
      for (int rq = 0; rq < 4; ++rq) {
        f32x4 rv = rp[(mi * 2 + nj) * 256 + rq * 64 + lane];
#pragma unroll
        for (int rl = 0; rl < 4; ++rl)
          s[mi][nj][rq * 4 + rl] = s[mi][nj][rq * 4 + rl] * scale + rv[rl];
      }

  // ---- softmax over k per q-col: 32 lane-local + one shfl_xor(32),
  //      P normalized IN REGISTERS (mirrored-PV requirement) ----
#pragma unroll
  for (int nj = 0; nj < 2; ++nj) {
    float mx = s[0][nj][0];
#pragma unroll
    for (int mi = 0; mi < 2; ++mi)
#pragma unroll
      for (int r = 0; r < 16; ++r)
        mx = fmaxf(mx, s[mi][nj][r]);
    mx = fmaxf(mx, __shfl_xor(mx, 32));
    float sum = 0.f;
#pragma unroll
    for (int mi = 0; mi < 2; ++mi)
#pragma unroll
      for (int r = 0; r < 16; ++r) {
        float p = __expf(s[mi][nj][r] - mx);
        s[mi][nj][r] = p;
        sum += p;
      }
    sum += __shfl_xor(sum, 32);
    float inv = __builtin_amdgcn_rcpf(sum);
#pragma unroll
    for (int mi = 0; mi < 2; ++mi)
#pragma unroll
      for (int r = 0; r < 16; ++r)
        s[mi][nj][r] *= inv;
  }

  // ---- O[q][d] = P V : A = in-register P frag, B = lazy V frag (kk=0..3) --
  // kk=3 full MFMA: P(k>=49)==0 exactly; V rows 49..63 = neighbor data * 0.
  f32x16 o[2] = {};
#pragma unroll
  for (int kk = 0; kk < 4; ++kk) {
    u16x8 tmp;
#pragma unroll
    for (int e = 0; e < 8; ++e)
      tmp[e] = vh[(kk * 16 + hi * 8 + e) * 32 + l31];
    bf16x8 vbk = __builtin_bit_cast(bf16x8, tmp);
    __builtin_amdgcn_s_setprio(1);
#pragma unroll
    for (int nj = 0; nj < 2; ++nj) {
      const int mi = kk >> 1, br = (kk & 1) * 8;
      unsigned t0 = pkbf(s[mi][nj][br + 0], s[mi][nj][br + 1]);
      unsigned t1 = pkbf(s[mi][nj][br + 2], s[mi][nj][br + 3]);
      unsigned t2 = pkbf(s[mi][nj][br + 4], s[mi][nj][br + 5]);
      unsigned t3 = pkbf(s[mi][nj][br + 6], s[mi][nj][br + 7]);
      asm("v_permlane32_swap_b32 %0, %1" : "+v"(t0), "+v"(t2));
      asm("v_permlane32_swap_b32 %0, %1" : "+v"(t1), "+v"(t3));
      uint4 uu; uu.x = t0; uu.y = t1; uu.z = t2; uu.w = t3;
      bf16x8 pa = __builtin_bit_cast(bf16x8, uu);
      o[nj] = __builtin_amdgcn_mfma_f32_32x32x16_bf16(pa, vbk, o[nj], 0, 0, 0);
    }
    __builtin_amdgcn_s_setprio(0);
  }

  // ---- store O[b, q, h*32 + d=l31] (coalesced; P already normalized) ----
  u16* obase = attnout + (size_t)b * (NTOK * DIM) + h * HD;
#pragma unroll
  for (int nj = 0; nj < 2; ++nj)
#pragma unroll
    for (int r = 0; r < 16; ++r) {
      int q = nj * 32 + (r & 3) + 8 * (r >> 2) + 4 * hi;
      if (q < NTOK)
        obase[(size_t)q * DIM + l31] = f2b(o[nj][r]);
    }
}

// ---------------------------------------------------------------------------
extern "C" void kernel_launch(void* const* d_in, const int* in_sizes, int n_in,
                              void* d_out, int out_size, void* d_ws, size_t ws_size,
                              hipStream_t stream) {
  const float* x       = (const float*)d_in[0];
  const float* qkv_w   = (const float*)d_in[1];
  const float* qkv_b   = (const float*)d_in[2];
  const float* proj_w  = (const float*)d_in[3];
  const float* proj_b  = (const float*)d_in[4];
  const float* bias_tb = (const float*)d_in[5];
  const float* mask    = (const float*)d_in[6];
  const int*   rel_idx = (const int*)d_in[7];
  float* out = (float*)d_out;

  char* ws = (char*)d_ws;
  u16*   xb      = (u16*)(ws + 0);                  //  77,070,336  x bf16
  u16*   wqkvb   = (u16*)(ws + 77070336);           //     884,736  qkv_w bf16
  u16*   wprojb  = (u16*)(ws + 77955072);           //     294,912  proj_w bf16
  float* rpbm    = (float*)(ws + 78249984);         //  12,582,912  bias+mask
  u16*   qkv     = (u16*)(ws + 90832896);           // 231,211,008  qkv head-major
  u16*   attnout = (u16*)(ws + 322043904);          //  77,070,336  attn out bf16

  // 1) prep: all casts + 32x32-layout bias+mask table
  k_prep<<<41280, 256, 0, stream>>>(x, xb, qkv_w, wqkvb, proj_w, wprojb,
                                    bias_tb, mask, rel_idx, rpbm);

  // 2) QKV GEMM (256x128, 8 waves) -> head-major qkv [3][12][2048][49][32]
  k_gemm256<1, 1152, 9, 441><<<3528, 512, 0, stream>>>(xb, wqkvb, qkv_b,
                                                       (void*)qkv);

  // 3) window attention (no LDS, mirrored PV, XCD-swizzled, setprio)
  k_attn<<<6144, 256, 0, stream>>>(qkv, rpbm, attnout);

  // 4) proj GEMM (256x128, 8 waves): [100352,384] x [384,384]^T -> f32 d_out
  k_gemm256<0, 384, 3, 147><<<1176, 512, 0, stream>>>(attnout, wprojb, proj_b,
                                                      (void*)out);

  (void)in_sizes; (void)n_in; (void)out_size; (void)ws_size;
}